// Round 10
// baseline (1206.939 us; speedup 1.0000x reference)
//
#include <hip/hip_runtime.h>
#include <hip/hip_bf16.h>

// ---------------------------------------------------------------------------
// Bidirectional GRU encoder (Keras reset_after=true), B=64 S=512 U=256 V=32000
// Round 10: MFMA recurrence, occupancy-fixed (R6 retry with lessons applied).
//   32 wgs = (dir, group of 4 batches); 256 thr = 4 waves; lb(256,1) ->
//   1 wave/SIMD, 512 unified regs/lane: U B-frags (384 regs) live in
//   VGPR+AGPR, MFMA-native (no move tax - the thing VALU rounds paid).
//   Per step: h[16x256] @ U[256x768] = 384 mfma_16x16x32 (96/wave, 12 slots
//   x 8 K-frags). Chains sit at C-rows {0,4,8,12} => lane group G owns chain
//   G, q=0 register => epilogue all-lane, fully lane-local, zero shuffles.
//   h: bf16 in XOR-swizzled double-buffered LDS (verified-free pattern),
//   1 barrier/step. gx pre-laid-out by k1 for 3x uint2 per-lane loads.
//   k0a wt_prep : W fp32 -> Wtb [dir][768][256] bf16
//   k0b u_prep  : U fp32 -> B-frag blobs [dir][w4][s12][kk8][lane64][8]
//   k1  gx_mfma : gx3 = emb[x] @ W + b_in (+b_rec z,r) in gru-lane order
//   k2  gru     : the recurrence
// ws: [0,100663296) gx3 ; +786432 Wtb ; +786432 Upk   (~102.2 MB)
// ---------------------------------------------------------------------------

typedef short short8 __attribute__((ext_vector_type(8)));
typedef float f32x4 __attribute__((ext_vector_type(4)));

__device__ __forceinline__ unsigned short f2bf(float f) {
  unsigned int u = __float_as_uint(f);
  return (unsigned short)((u + 0x7fffu + ((u >> 16) & 1u)) >> 16);  // RNE
}
__device__ __forceinline__ float blo(unsigned int u) { return __uint_as_float(u << 16); }
__device__ __forceinline__ float bhi(unsigned int u) { return __uint_as_float(u & 0xffff0000u); }
__device__ __forceinline__ float sigf(float x) {
  return __builtin_amdgcn_rcpf(1.f + __expf(-x));
}
__device__ __forceinline__ float tanhfast(float x) {
  return 1.f - 2.f * __builtin_amdgcn_rcpf(1.f + __expf(2.f * x));
}

// ---------------- k0a: Wtb[dir][c][k] = bf16(W[k][c]) -----------------------
__global__ void __launch_bounds__(256) wt_prep_kernel(const float* __restrict__ Wf,
                                                      const float* __restrict__ Wb,
                                                      unsigned short* __restrict__ Wtb) {
  int o = blockIdx.x * 256 + threadIdx.x;
  if (o >= 2 * 768 * 256) return;
  int dir = o / (768 * 256);
  int rem = o % (768 * 256);
  int c = rem / 256, k = rem % 256;
  const float* W = dir ? Wb : Wf;
  Wtb[o] = f2bf(W[(size_t)k * 768 + c]);
}

// ---------------- k0b: U -> MFMA B-fragments --------------------------------
// id = (((dir*4+w)*12+s)*8+kk)*64+lane, 8 shorts each.
// s = g*4+s2: unit = w*64 + s2*16 + (lane&15), gcol = g*256 + unit,
// k = kk*32 + (lane>>4)*8 + e.   (R6-verified B layout)
__global__ void __launch_bounds__(256) u_prep_kernel(const float* __restrict__ Uf,
                                                     const float* __restrict__ Ub,
                                                     unsigned short* __restrict__ Upk) {
  int id = blockIdx.x * 256 + threadIdx.x;
  if (id >= 2 * 4 * 12 * 8 * 64) return;  // 49152
  int lane = id & 63;
  int kk = (id >> 6) & 7;
  int s = (id >> 9) % 12;
  int w = (id / (64 * 8 * 12)) & 3;
  int dir = id / (64 * 8 * 12 * 4);
  const float* U = dir ? Ub : Uf;
  int g = s >> 2, s2 = s & 3;
  int gcol = g * 256 + w * 64 + s2 * 16 + (lane & 15);
  int k0 = kk * 32 + (lane >> 4) * 8;
  unsigned short* o = Upk + (size_t)id * 8;
#pragma unroll
  for (int e = 0; e < 8; ++e) o[e] = f2bf(U[(size_t)(k0 + e) * 768 + gcol]);
}

// ---------------- k1: gx3 = emb[x] @ W + bias, bf16 MFMA --------------------
// Output layout: [dir][t][bg16][w4][lane64][12]: lane = c*16+cl holds, for
// chain c, slots p = g*4+s2 (unit = w*64+s2*16+cl).
__global__ void __launch_bounds__(256) gx_mfma_kernel(
    const int* __restrict__ x, const float* __restrict__ emb,
    const unsigned short* __restrict__ Wtb,
    const float* __restrict__ bfv, const float* __restrict__ bbv,
    unsigned short* __restrict__ gx3) {
  __shared__ __align__(16) unsigned short As[128 * 32];
  __shared__ __align__(16) unsigned short Bs[128 * 32];
  __shared__ int xid[128];

  int tid = threadIdx.x;
  int r0 = blockIdx.x * 128;
  int yt = blockIdx.y;
  int dir = (yt >= 6) ? 1 : 0;
  int c0 = (yt - dir * 6) * 128;
  const float* bv = dir ? bbv : bfv;
  const unsigned short* WtD = Wtb + (size_t)dir * 768 * 256;

  if (tid < 128) xid[tid] = x[r0 + tid];
  __syncthreads();

  int lane = tid & 63, w = tid >> 6;
  int wr = w >> 1, wc = w & 1;

  f32x4 acc[4][4] = {};

  for (int ks = 0; ks < 8; ++ks) {
#pragma unroll
    for (int i = 0; i < 2; ++i) {
      int s = tid + i * 256;
      int row = s >> 2, kslot = s & 3;
      int sw = kslot ^ ((row >> 2) & 3);
      const float* src = emb + (size_t)xid[row] * 256 + ks * 32 + kslot * 8;
      float4 f0 = *(const float4*)src;
      float4 f1 = *(const float4*)(src + 4);
      uint4 pa;
      pa.x = f2bf(f0.x) | ((unsigned)f2bf(f0.y) << 16);
      pa.y = f2bf(f0.z) | ((unsigned)f2bf(f0.w) << 16);
      pa.z = f2bf(f1.x) | ((unsigned)f2bf(f1.y) << 16);
      pa.w = f2bf(f1.z) | ((unsigned)f2bf(f1.w) << 16);
      *(uint4*)&As[row * 32 + sw * 8] = pa;
      uint4 pb = *(const uint4*)(WtD + (size_t)(c0 + row) * 256 + ks * 32 + kslot * 8);
      *(uint4*)&Bs[row * 32 + sw * 8] = pb;
    }
    __syncthreads();

    short8 a[4], b[4];
#pragma unroll
    for (int f = 0; f < 4; ++f) {
      int rowA = wr * 64 + f * 16 + (lane & 15);
      int swA = (lane >> 4) ^ ((rowA >> 2) & 3);
      a[f] = __builtin_bit_cast(short8, *(const uint4*)&As[rowA * 32 + swA * 8]);
      int rowB = wc * 64 + f * 16 + (lane & 15);
      int swB = (lane >> 4) ^ ((rowB >> 2) & 3);
      b[f] = __builtin_bit_cast(short8, *(const uint4*)&Bs[rowB * 32 + swB * 8]);
    }
#pragma unroll
    for (int fm = 0; fm < 4; ++fm)
#pragma unroll
      for (int fn = 0; fn < 4; ++fn)
        acc[fm][fn] = __builtin_amdgcn_mfma_f32_16x16x32_bf16(a[fm], b[fn], acc[fm][fn], 0, 0, 0);
    __syncthreads();
  }

#pragma unroll
  for (int fn = 0; fn < 4; ++fn) {
    int col = c0 + wc * 64 + fn * 16 + (lane & 15);
    float bias = bv[col] + (col < 512 ? bv[768 + col] : 0.f);
    int g = col >> 8, u = col & 255;
    int w2 = u >> 6, s2 = (u >> 4) & 3, cl2 = u & 15;
    int p = g * 4 + s2;
#pragma unroll
    for (int fm = 0; fm < 4; ++fm) {
      int rowb = r0 + wr * 64 + fm * 16 + (lane >> 4) * 4;
#pragma unroll
      for (int q = 0; q < 4; ++q) {
        int row = rowb + q;
        int bb2 = row >> 9, tt2 = row & 511;
        int c = bb2 & 3, bg2 = bb2 >> 2;
        size_t idx = (((size_t)(dir * 512 + tt2) * 16 + bg2) * 4 + w2) * 768
                     + (size_t)(c * 16 + cl2) * 12 + p;
        gx3[idx] = f2bf(acc[fm][fn][q] + bias);
      }
    }
  }
}

// ---------------- k2: MFMA recurrence, 32 wgs x 4 chains --------------------
__global__ void __launch_bounds__(256, 1) gru_kernel(
    const unsigned short* __restrict__ Upk,
    const unsigned short* __restrict__ gx3,
    const int* __restrict__ x,
    const float* __restrict__ bfv, const float* __restrict__ bbv,
    float* __restrict__ out) {
  int wg = blockIdx.x;                 // 0..31
  int dir = wg >> 4, bg = wg & 15;
  int tid = threadIdx.x;
  int w = tid >> 6, l = tid & 63;
  int G = l >> 4, cl = l & 15;         // chain-in-group, unit-col
  int b = bg * 4 + G;

  // h[16 rows][256 units] bf16, XOR-swizzled (byte ^= (row&7)<<4 within the
  // 512B row), double-buffered. Chains at rows {0,4,8,12}; others stay 0.
  __shared__ __align__(16) unsigned short h_lds[2][4096];

  // resident U B-fragments: 12 slots x 8 K-frags (384 regs, MFMA-native)
  short8 Ufr[12][8];
  {
    const unsigned short* ub = Upk + (size_t)(dir * 4 + w) * 49152 + (size_t)l * 8;
#pragma unroll
    for (int s = 0; s < 12; ++s)
#pragma unroll
      for (int kk = 0; kk < 8; ++kk)
        Ufr[s][kk] = __builtin_bit_cast(short8, *(const uint4*)(ub + (s * 8 + kk) * 512));
  }

  {
    uint4 z = {0u, 0u, 0u, 0u};
    ((uint4*)h_lds)[tid] = z;
    ((uint4*)h_lds)[256 + tid] = z;
    ((uint4*)h_lds)[512 + tid] = z;
    ((uint4*)h_lds)[768 + tid] = z;
  }

  const float* bv = dir ? bbv : bfv;
  float brh[4];
#pragma unroll
  for (int s2 = 0; s2 < 4; ++s2) brh[s2] = bv[1280 + w * 64 + s2 * 16 + cl];
  const int* xb = x + b * 512;
  float* outb = out + ((size_t)b << 17);
  const unsigned short* gxb = gx3 + (size_t)((bg * 4 + w) * 64 + l) * 12;

  int amask = (cl & 7) << 4;
  float h_old[4] = {0.f, 0.f, 0.f, 0.f};
  __syncthreads();

  int cur = 0;
  for (int step = 0; step < 512; ++step) {
    int tcur = dir ? (511 - step) : step;
    // gx + mask loads: issued before MFMA phase, consumed after (latency hidden)
    const unsigned short* g = gxb + (size_t)(dir * 512 + tcur) * 49152;
    uint2 gz2 = *(const uint2*)(g);        // z: s2 0..3
    uint2 gr2 = *(const uint2*)(g + 4);    // r
    uint2 gh2 = *(const uint2*)(g + 8);    // h
    int xv = xb[tcur];

    // MFMA phase: acc[s] = h @ U[slot s]; lane reads A row cl, k-seg G.
    f32x4 acc[12];
#pragma unroll
    for (int s = 0; s < 12; ++s) acc[s] = (f32x4){0.f, 0.f, 0.f, 0.f};
    const char* hb = (const char*)(&h_lds[cur][0]);
#pragma unroll
    for (int kk = 0; kk < 8; ++kk) {
      short8 a = __builtin_bit_cast(short8,
          *(const uint4*)(hb + cl * 512 + (((kk << 6) | (G << 4)) ^ amask)));
#pragma unroll
      for (int s = 0; s < 12; ++s)
        acc[s] = __builtin_amdgcn_mfma_f32_16x16x32_bf16(a, Ufr[s][kk], acc[s], 0, 0, 0);
    }

    // epilogue: chain G lives in C row 4G = (l>>4)*4 + 0 -> acc[s][0]
    unsigned short* hw = &h_lds[cur ^ 1][0];
    unsigned int gus[6] = {gz2.x, gz2.y, gr2.x, gr2.y, gh2.x, gh2.y};
#pragma unroll
    for (int s2 = 0; s2 < 4; ++s2) {
      float gz = (s2 & 1) ? bhi(gus[s2 >> 1]) : blo(gus[s2 >> 1]);
      float gr = (s2 & 1) ? bhi(gus[2 + (s2 >> 1)]) : blo(gus[2 + (s2 >> 1)]);
      float gh = (s2 & 1) ? bhi(gus[4 + (s2 >> 1)]) : blo(gus[4 + (s2 >> 1)]);
      float z = sigf(gz + acc[s2][0]);
      float r = sigf(gr + acc[4 + s2][0]);
      float hh = tanhfast(gh + r * (acc[8 + s2][0] + brh[s2]));
      float hn = hh + z * (h_old[s2] - hh);
      hn = (xv == 0) ? h_old[s2] : hn;         // masked: carry state
      h_old[s2] = hn;
      int ub2 = (w * 128 + s2 * 32 + cl * 2) ^ ((G & 1) << 6);  // row 4G swizzle
      *(unsigned short*)((char*)hw + G * 2048 + ub2) = f2bf(hn);
      atomicAdd(&outb[(size_t)tcur * 256 + (w * 64 + s2 * 16 + cl)], hn);
    }
    __syncthreads();                            // one barrier per step
    cur ^= 1;
  }
}

// ---------------------------------------------------------------------------
extern "C" void kernel_launch(void* const* d_in, const int* in_sizes, int n_in,
                              void* d_out, int out_size, void* d_ws, size_t ws_size,
                              hipStream_t stream) {
  const int*   x   = (const int*)d_in[0];
  const float* emb = (const float*)d_in[1];
  const float* Wf  = (const float*)d_in[2];
  const float* Uf  = (const float*)d_in[3];
  const float* bf_ = (const float*)d_in[4];
  const float* Wb  = (const float*)d_in[5];
  const float* Ub  = (const float*)d_in[6];
  const float* bb_ = (const float*)d_in[7];
  float* out = (float*)d_out;

  unsigned short* gx3 = (unsigned short*)d_ws;                        // 100663296 B
  unsigned short* Wtb = (unsigned short*)((char*)d_ws + 100663296);   // 786432 B
  unsigned short* Upk = (unsigned short*)((char*)d_ws + 100663296 + 786432);  // 786432 B

  hipMemsetAsync(d_out, 0, (size_t)out_size * sizeof(float), stream);

  wt_prep_kernel<<<1536, 256, 0, stream>>>(Wf, Wb, Wtb);
  u_prep_kernel<<<192, 256, 0, stream>>>(Uf, Ub, Upk);
  gx_mfma_kernel<<<dim3(256, 12), 256, 0, stream>>>(x, emb, Wtb, bf_, bb_, gx3);
  gru_kernel<<<32, 256, 0, stream>>>(Upk, gx3, x, bf_, bb_, out);
}

// Round 11
// 691.785 us; speedup vs baseline: 1.7447x; 1.7447x over previous
//
#include <hip/hip_runtime.h>
#include <hip/hip_bf16.h>

// ---------------------------------------------------------------------------
// Bidirectional GRU encoder (Keras reset_after=true), B=64 S=512 U=256 V=32000
// Round 11: MFMA recurrence, schedule-fixed.
//   32 wgs = (dir, group of 4 batches); 512 thr = 8 waves (2/SIMD, lb(512,1)
//   -> 256-VGPR cap). Wave w owns 6 N-slots (gates z,r,h x col-groups
//   {2w, 2w+1}): U B-frags = 6x8 short8 = 192 regs resident.
//   Per step/wave: 8x(swizzled ds_read_b128 A-frag) + 48 MFMA; chains sit at
//   C rows {0,4,8,12} -> lane (G,cl) reads acc[s][0], fully lane-local
//   epilogue, 2 units/lane, 1 barrier/step. gx + mask PREFETCHED 1 step
//   ahead (R10's missing piece: ~900 cyc exposed latency -> hidden).
//   k0a wt_prep : W fp32 -> Wtb [dir][768][256] bf16
//   k0b u_prep  : U fp32 -> B-frag blobs [dir][w8][s6][kk8][lane64][8]
//   k1  gx_mfma : gx3 = emb[x] @ W + b_in (+b_rec z,r) in gru-lane order
//                 [dir][t][bg16][w8][lane64][6]
//   k2  gru     : the recurrence
// ws: [0,100663296) gx3 ; +786432 Wtb ; +786432 Upk   (~102.2 MB)
// ---------------------------------------------------------------------------

typedef short short8 __attribute__((ext_vector_type(8)));
typedef float f32x4 __attribute__((ext_vector_type(4)));

__device__ __forceinline__ unsigned short f2bf(float f) {
  unsigned int u = __float_as_uint(f);
  return (unsigned short)((u + 0x7fffu + ((u >> 16) & 1u)) >> 16);  // RNE
}
__device__ __forceinline__ float blo(unsigned int u) { return __uint_as_float(u << 16); }
__device__ __forceinline__ float bhi(unsigned int u) { return __uint_as_float(u & 0xffff0000u); }
__device__ __forceinline__ float sigf(float x) {
  return __builtin_amdgcn_rcpf(1.f + __expf(-x));
}
__device__ __forceinline__ float tanhfast(float x) {
  return 1.f - 2.f * __builtin_amdgcn_rcpf(1.f + __expf(2.f * x));
}

// ---------------- k0a: Wtb[dir][c][k] = bf16(W[k][c]) -----------------------
__global__ void __launch_bounds__(256) wt_prep_kernel(const float* __restrict__ Wf,
                                                      const float* __restrict__ Wb,
                                                      unsigned short* __restrict__ Wtb) {
  int o = blockIdx.x * 256 + threadIdx.x;
  if (o >= 2 * 768 * 256) return;
  int dir = o / (768 * 256);
  int rem = o % (768 * 256);
  int c = rem / 256, k = rem % 256;
  const float* W = dir ? Wb : Wf;
  Wtb[o] = f2bf(W[(size_t)k * 768 + c]);
}

// ---------------- k0b: U -> MFMA B-fragments (8-wave split) -----------------
// id = (((dir*8+w)*6+s)*8+kk)*64+lane, 8 shorts each. s = g*2+d:
// gcol = g*256 + w*32 + d*16 + (lane&15), k = kk*32 + (lane>>4)*8 + e.
__global__ void __launch_bounds__(256) u_prep_kernel(const float* __restrict__ Uf,
                                                     const float* __restrict__ Ub,
                                                     unsigned short* __restrict__ Upk) {
  int id = blockIdx.x * 256 + threadIdx.x;
  if (id >= 2 * 8 * 6 * 8 * 64) return;  // 49152
  int lane = id & 63;
  int kk = (id >> 6) & 7;
  int s = (id >> 9) % 6;
  int w = (id / 3072) & 7;
  int dir = id / 24576;
  const float* U = dir ? Ub : Uf;
  int g = s >> 1, d = s & 1;
  int gcol = g * 256 + w * 32 + d * 16 + (lane & 15);
  int k0 = kk * 32 + (lane >> 4) * 8;
  unsigned short* o = Upk + (size_t)id * 8;
#pragma unroll
  for (int e = 0; e < 8; ++e) o[e] = f2bf(U[(size_t)(k0 + e) * 768 + gcol]);
}

// ---------------- k1: gx3 = emb[x] @ W + bias, bf16 MFMA --------------------
// Output layout: [dir][t][bg16][w8][lane64][6]; lane = G*16+cl holds slots
// s = g*2+d for chain bg*4+G, unit w*32+d*16+cl.
__global__ void __launch_bounds__(256) gx_mfma_kernel(
    const int* __restrict__ x, const float* __restrict__ emb,
    const unsigned short* __restrict__ Wtb,
    const float* __restrict__ bfv, const float* __restrict__ bbv,
    unsigned short* __restrict__ gx3) {
  __shared__ __align__(16) unsigned short As[128 * 32];
  __shared__ __align__(16) unsigned short Bs[128 * 32];
  __shared__ int xid[128];

  int tid = threadIdx.x;
  int r0 = blockIdx.x * 128;
  int yt = blockIdx.y;
  int dir = (yt >= 6) ? 1 : 0;
  int c0 = (yt - dir * 6) * 128;
  const float* bv = dir ? bbv : bfv;
  const unsigned short* WtD = Wtb + (size_t)dir * 768 * 256;

  if (tid < 128) xid[tid] = x[r0 + tid];
  __syncthreads();

  int lane = tid & 63, w = tid >> 6;
  int wr = w >> 1, wc = w & 1;

  f32x4 acc[4][4] = {};

  for (int ks = 0; ks < 8; ++ks) {
#pragma unroll
    for (int i = 0; i < 2; ++i) {
      int s = tid + i * 256;
      int row = s >> 2, kslot = s & 3;
      int sw = kslot ^ ((row >> 2) & 3);
      const float* src = emb + (size_t)xid[row] * 256 + ks * 32 + kslot * 8;
      float4 f0 = *(const float4*)src;
      float4 f1 = *(const float4*)(src + 4);
      uint4 pa;
      pa.x = f2bf(f0.x) | ((unsigned)f2bf(f0.y) << 16);
      pa.y = f2bf(f0.z) | ((unsigned)f2bf(f0.w) << 16);
      pa.z = f2bf(f1.x) | ((unsigned)f2bf(f1.y) << 16);
      pa.w = f2bf(f1.z) | ((unsigned)f2bf(f1.w) << 16);
      *(uint4*)&As[row * 32 + sw * 8] = pa;
      uint4 pb = *(const uint4*)(WtD + (size_t)(c0 + row) * 256 + ks * 32 + kslot * 8);
      *(uint4*)&Bs[row * 32 + sw * 8] = pb;
    }
    __syncthreads();

    short8 a[4], b[4];
#pragma unroll
    for (int f = 0; f < 4; ++f) {
      int rowA = wr * 64 + f * 16 + (lane & 15);
      int swA = (lane >> 4) ^ ((rowA >> 2) & 3);
      a[f] = __builtin_bit_cast(short8, *(const uint4*)&As[rowA * 32 + swA * 8]);
      int rowB = wc * 64 + f * 16 + (lane & 15);
      int swB = (lane >> 4) ^ ((rowB >> 2) & 3);
      b[f] = __builtin_bit_cast(short8, *(const uint4*)&Bs[rowB * 32 + swB * 8]);
    }
#pragma unroll
    for (int fm = 0; fm < 4; ++fm)
#pragma unroll
      for (int fn = 0; fn < 4; ++fn)
        acc[fm][fn] = __builtin_amdgcn_mfma_f32_16x16x32_bf16(a[fm], b[fn], acc[fm][fn], 0, 0, 0);
    __syncthreads();
  }

#pragma unroll
  for (int fn = 0; fn < 4; ++fn) {
    int col = c0 + wc * 64 + fn * 16 + (lane & 15);
    float bias = bv[col] + (col < 512 ? bv[768 + col] : 0.f);
    int g = col >> 8, u = col & 255;
    int w2 = u >> 5, d = (u >> 4) & 1, cl2 = u & 15;
    int s = g * 2 + d;
#pragma unroll
    for (int fm = 0; fm < 4; ++fm) {
      int rowb = r0 + wr * 64 + fm * 16 + (lane >> 4) * 4;
#pragma unroll
      for (int q = 0; q < 4; ++q) {
        int row = rowb + q;
        int bb2 = row >> 9, tt2 = row & 511;
        int G = bb2 & 3, bg2 = bb2 >> 2;
        size_t idx = ((((size_t)(dir * 512 + tt2) * 16 + bg2) * 8 + w2) * 64
                      + (G * 16 + cl2)) * 6 + s;
        gx3[idx] = f2bf(acc[fm][fn][q] + bias);
      }
    }
  }
}

// ---------------- k2: MFMA recurrence, 8 waves, prefetch-ahead --------------
__global__ void __launch_bounds__(512, 1) gru_kernel(
    const unsigned short* __restrict__ Upk,
    const unsigned short* __restrict__ gx3,
    const int* __restrict__ x,
    const float* __restrict__ bfv, const float* __restrict__ bbv,
    float* __restrict__ out) {
  int wg = blockIdx.x;                 // 0..31
  int dir = wg >> 4, bg = wg & 15;
  int tid = threadIdx.x;
  int w = tid >> 6, l = tid & 63;
  int G = l >> 4, cl = l & 15;         // chain-in-group, unit-col
  int b = bg * 4 + G;

  // h[16 rows][256 units] bf16, byte ^= ((row&7)<<4) swizzle, double-buffered
  __shared__ __align__(16) unsigned short h_lds[2][4096];

  // resident U B-fragments: 6 slots x 8 K-frags = 192 regs
  short8 Ufr[6][8];
  {
    const unsigned short* ub = Upk + (size_t)(dir * 8 + w) * 24576 + (size_t)l * 8;
#pragma unroll
    for (int s = 0; s < 6; ++s)
#pragma unroll
      for (int kk = 0; kk < 8; ++kk)
        Ufr[s][kk] = __builtin_bit_cast(short8, *(const uint4*)(ub + (s * 8 + kk) * 512));
  }

  {
    uint4 z = {0u, 0u, 0u, 0u};
    ((uint4*)h_lds)[tid] = z;
    ((uint4*)h_lds)[512 + tid] = z;
  }

  const float* bv = dir ? bbv : bfv;
  float brh[2];
#pragma unroll
  for (int d = 0; d < 2; ++d) brh[d] = bv[1280 + w * 32 + d * 16 + cl];
  const int* xb = x + b * 512;
  float* outb = out + ((size_t)b << 17);
  const unsigned short* gxb = gx3 + ((size_t)bg * 8 + w) * 384 + (size_t)l * 6;

  int amask = (cl & 7) << 4;
  float h_old[2] = {0.f, 0.f};

  // prologue: prefetch step 0's gx + mask
  int t0 = dir ? 511 : 0;
  unsigned int gq0, gq1, gq2;
  int xv;
  {
    const unsigned short* g = gxb + (size_t)(dir * 512 + t0) * 49152;
    gq0 = *(const unsigned int*)(g);       // z: d=0 lo, d=1 hi
    gq1 = *(const unsigned int*)(g + 2);   // r
    gq2 = *(const unsigned int*)(g + 4);   // h
    xv = xb[t0];
  }
  __syncthreads();

  int cur = 0;
  for (int step = 0; step < 512; ++step) {
    int tcur = dir ? (511 - step) : step;
    // prefetch NEXT step's gx + mask (consumed next iteration)
    int sn = (step < 511) ? step + 1 : 511;
    int tn = dir ? (511 - sn) : sn;
    unsigned int gn0, gn1, gn2;
    int xn;
    {
      const unsigned short* g = gxb + (size_t)(dir * 512 + tn) * 49152;
      gn0 = *(const unsigned int*)(g);
      gn1 = *(const unsigned int*)(g + 2);
      gn2 = *(const unsigned int*)(g + 4);
      xn = xb[tn];
    }

    // --- MFMA phase: acc[s] = h @ U[slot s] ---
    f32x4 acc[6];
#pragma unroll
    for (int s = 0; s < 6; ++s) acc[s] = (f32x4){0.f, 0.f, 0.f, 0.f};
    const char* hb = (const char*)(&h_lds[cur][0]);
#pragma unroll
    for (int kk = 0; kk < 8; ++kk) {
      short8 a = __builtin_bit_cast(short8,
          *(const uint4*)(hb + cl * 512 + (((kk << 6) | (G << 4)) ^ amask)));
#pragma unroll
      for (int s = 0; s < 6; ++s)
        acc[s] = __builtin_amdgcn_mfma_f32_16x16x32_bf16(a, Ufr[s][kk], acc[s], 0, 0, 0);
    }

    // --- epilogue: chain G at C row 4G -> acc[s][0]; 2 units/lane ---
    char* hw = (char*)(&h_lds[cur ^ 1][0]);
#pragma unroll
    for (int d = 0; d < 2; ++d) {
      float gz = d ? bhi(gq0) : blo(gq0);
      float gr = d ? bhi(gq1) : blo(gq1);
      float gh = d ? bhi(gq2) : blo(gq2);
      float z = sigf(gz + acc[0 + d][0]);
      float r = sigf(gr + acc[2 + d][0]);
      float hh = tanhfast(gh + r * (acc[4 + d][0] + brh[d]));
      float hn = hh + z * (h_old[d] - hh);
      hn = (xv == 0) ? h_old[d] : hn;          // masked: carry state
      h_old[d] = hn;
      int u = w * 32 + d * 16 + cl;
      *(unsigned short*)(hw + G * 2048 + ((u * 2) ^ ((G & 1) << 6))) = f2bf(hn);
      atomicAdd(&outb[(size_t)tcur * 256 + u], hn);
    }
    __syncthreads();                            // one barrier per step
    gq0 = gn0; gq1 = gn1; gq2 = gn2; xv = xn;
    cur ^= 1;
  }
}

// ---------------------------------------------------------------------------
extern "C" void kernel_launch(void* const* d_in, const int* in_sizes, int n_in,
                              void* d_out, int out_size, void* d_ws, size_t ws_size,
                              hipStream_t stream) {
  const int*   x   = (const int*)d_in[0];
  const float* emb = (const float*)d_in[1];
  const float* Wf  = (const float*)d_in[2];
  const float* Uf  = (const float*)d_in[3];
  const float* bf_ = (const float*)d_in[4];
  const float* Wb  = (const float*)d_in[5];
  const float* Ub  = (const float*)d_in[6];
  const float* bb_ = (const float*)d_in[7];
  float* out = (float*)d_out;

  unsigned short* gx3 = (unsigned short*)d_ws;                        // 100663296 B
  unsigned short* Wtb = (unsigned short*)((char*)d_ws + 100663296);   // 786432 B
  unsigned short* Upk = (unsigned short*)((char*)d_ws + 100663296 + 786432);  // 786432 B

  hipMemsetAsync(d_out, 0, (size_t)out_size * sizeof(float), stream);

  wt_prep_kernel<<<1536, 256, 0, stream>>>(Wf, Wb, Wtb);
  u_prep_kernel<<<192, 256, 0, stream>>>(Uf, Ub, Upk);
  gx_mfma_kernel<<<dim3(256, 12), 256, 0, stream>>>(x, emb, Wtb, bf_, bb_, gx3);
  gru_kernel<<<32, 512, 0, stream>>>(Upk, gx3, x, bf_, bb_, out);
}

// Round 12
// 606.083 us; speedup vs baseline: 1.9914x; 1.1414x over previous
//
#include <hip/hip_runtime.h>
#include <hip/hip_bf16.h>

// ---------------------------------------------------------------------------
// Bidirectional GRU encoder (Keras reset_after=true), B=64 S=512 U=256 V=32000
// Round 12 = R11 + serial-overhead removal:
//   (a) raw s_barrier (lgkmcnt(0) only) -> no per-step vmcnt(0) drain of the
//       2 atomics + 4 prefetch loads (HK technique; rule-18 sched_barriers)
//   (b) gx SoA layout [dir][t][gate3][8192 dwords]: coalesced prefetch +
//       running byte pointer (no per-step 64-bit muls)
//   32 wgs = (dir, 4-batch group); 512 thr = 8 waves (2/SIMD, lb(512,1)).
//   Wave w owns 6 N-slots; U B-frags 6x8 short8 = 192 regs resident.
//   Chains at C rows {0,4,8,12}; lane-local epilogue; 1 barrier/step.
// ws: [0,100663296) gx4 ; +786432 Wtb ; +786432 Upk   (~102.2 MB)
// ---------------------------------------------------------------------------

typedef short short8 __attribute__((ext_vector_type(8)));
typedef float f32x4 __attribute__((ext_vector_type(4)));

__device__ __forceinline__ unsigned short f2bf(float f) {
  unsigned int u = __float_as_uint(f);
  return (unsigned short)((u + 0x7fffu + ((u >> 16) & 1u)) >> 16);  // RNE
}
__device__ __forceinline__ float blo(unsigned int u) { return __uint_as_float(u << 16); }
__device__ __forceinline__ float bhi(unsigned int u) { return __uint_as_float(u & 0xffff0000u); }
__device__ __forceinline__ float sigf(float x) {
  return __builtin_amdgcn_rcpf(1.f + __expf(-x));
}
__device__ __forceinline__ float tanhfast(float x) {
  return 1.f - 2.f * __builtin_amdgcn_rcpf(1.f + __expf(2.f * x));
}
// LDS-only barrier: order h_lds exchange without draining vmem queues.
__device__ __forceinline__ void lds_barrier() {
  __builtin_amdgcn_sched_barrier(0);
  asm volatile("s_waitcnt lgkmcnt(0)" ::: "memory");
  __builtin_amdgcn_s_barrier();
  __builtin_amdgcn_sched_barrier(0);
}

// ---------------- k0a: Wtb[dir][c][k] = bf16(W[k][c]) -----------------------
__global__ void __launch_bounds__(256) wt_prep_kernel(const float* __restrict__ Wf,
                                                      const float* __restrict__ Wb,
                                                      unsigned short* __restrict__ Wtb) {
  int o = blockIdx.x * 256 + threadIdx.x;
  if (o >= 2 * 768 * 256) return;
  int dir = o / (768 * 256);
  int rem = o % (768 * 256);
  int c = rem / 256, k = rem % 256;
  const float* W = dir ? Wb : Wf;
  Wtb[o] = f2bf(W[(size_t)k * 768 + c]);
}

// ---------------- k0b: U -> MFMA B-fragments (8-wave split) -----------------
// id = (((dir*8+w)*6+s)*8+kk)*64+lane. s = g*2+d:
// gcol = g*256 + w*32 + d*16 + (lane&15), k = kk*32 + (lane>>4)*8 + e.
__global__ void __launch_bounds__(256) u_prep_kernel(const float* __restrict__ Uf,
                                                     const float* __restrict__ Ub,
                                                     unsigned short* __restrict__ Upk) {
  int id = blockIdx.x * 256 + threadIdx.x;
  if (id >= 2 * 8 * 6 * 8 * 64) return;  // 49152
  int lane = id & 63;
  int kk = (id >> 6) & 7;
  int s = (id >> 9) % 6;
  int w = (id / 3072) & 7;
  int dir = id / 24576;
  const float* U = dir ? Ub : Uf;
  int g = s >> 1, d = s & 1;
  int gcol = g * 256 + w * 32 + d * 16 + (lane & 15);
  int k0 = kk * 32 + (lane >> 4) * 8;
  unsigned short* o = Upk + (size_t)id * 8;
#pragma unroll
  for (int e = 0; e < 8; ++e) o[e] = f2bf(U[(size_t)(k0 + e) * 768 + gcol]);
}

// ---------------- k1: gx4 = emb[x] @ W + bias, bf16 MFMA, SoA out -----------
// gx4 ushort idx = ((dir*512+t)*3+g)*16384 + ((bg*8+w2)*64 + G*16+cl2)*2 + d
__global__ void __launch_bounds__(256) gx_mfma_kernel(
    const int* __restrict__ x, const float* __restrict__ emb,
    const unsigned short* __restrict__ Wtb,
    const float* __restrict__ bfv, const float* __restrict__ bbv,
    unsigned short* __restrict__ gx4) {
  __shared__ __align__(16) unsigned short As[128 * 32];
  __shared__ __align__(16) unsigned short Bs[128 * 32];
  __shared__ int xid[128];

  int tid = threadIdx.x;
  int r0 = blockIdx.x * 128;
  int yt = blockIdx.y;
  int dir = (yt >= 6) ? 1 : 0;
  int c0 = (yt - dir * 6) * 128;
  const float* bv = dir ? bbv : bfv;
  const unsigned short* WtD = Wtb + (size_t)dir * 768 * 256;

  if (tid < 128) xid[tid] = x[r0 + tid];
  __syncthreads();

  int lane = tid & 63, w = tid >> 6;
  int wr = w >> 1, wc = w & 1;

  f32x4 acc[4][4] = {};

  for (int ks = 0; ks < 8; ++ks) {
#pragma unroll
    for (int i = 0; i < 2; ++i) {
      int s = tid + i * 256;
      int row = s >> 2, kslot = s & 3;
      int sw = kslot ^ ((row >> 2) & 3);
      const float* src = emb + (size_t)xid[row] * 256 + ks * 32 + kslot * 8;
      float4 f0 = *(const float4*)src;
      float4 f1 = *(const float4*)(src + 4);
      uint4 pa;
      pa.x = f2bf(f0.x) | ((unsigned)f2bf(f0.y) << 16);
      pa.y = f2bf(f0.z) | ((unsigned)f2bf(f0.w) << 16);
      pa.z = f2bf(f1.x) | ((unsigned)f2bf(f1.y) << 16);
      pa.w = f2bf(f1.z) | ((unsigned)f2bf(f1.w) << 16);
      *(uint4*)&As[row * 32 + sw * 8] = pa;
      uint4 pb = *(const uint4*)(WtD + (size_t)(c0 + row) * 256 + ks * 32 + kslot * 8);
      *(uint4*)&Bs[row * 32 + sw * 8] = pb;
    }
    __syncthreads();

    short8 a[4], b[4];
#pragma unroll
    for (int f = 0; f < 4; ++f) {
      int rowA = wr * 64 + f * 16 + (lane & 15);
      int swA = (lane >> 4) ^ ((rowA >> 2) & 3);
      a[f] = __builtin_bit_cast(short8, *(const uint4*)&As[rowA * 32 + swA * 8]);
      int rowB = wc * 64 + f * 16 + (lane & 15);
      int swB = (lane >> 4) ^ ((rowB >> 2) & 3);
      b[f] = __builtin_bit_cast(short8, *(const uint4*)&Bs[rowB * 32 + swB * 8]);
    }
#pragma unroll
    for (int fm = 0; fm < 4; ++fm)
#pragma unroll
      for (int fn = 0; fn < 4; ++fn)
        acc[fm][fn] = __builtin_amdgcn_mfma_f32_16x16x32_bf16(a[fm], b[fn], acc[fm][fn], 0, 0, 0);
    __syncthreads();
  }

#pragma unroll
  for (int fn = 0; fn < 4; ++fn) {
    int col = c0 + wc * 64 + fn * 16 + (lane & 15);
    float bias = bv[col] + (col < 512 ? bv[768 + col] : 0.f);
    int g = col >> 8, u = col & 255;
    int w2 = u >> 5, d = (u >> 4) & 1, cl2 = u & 15;
#pragma unroll
    for (int fm = 0; fm < 4; ++fm) {
      int rowb = r0 + wr * 64 + fm * 16 + (lane >> 4) * 4;
#pragma unroll
      for (int q = 0; q < 4; ++q) {
        int row = rowb + q;
        int bb2 = row >> 9, tt2 = row & 511;
        int G = bb2 & 3, bg2 = bb2 >> 2;
        size_t idx = ((size_t)(dir * 512 + tt2) * 3 + g) * 16384
                     + (size_t)((bg2 * 8 + w2) * 64 + (G * 16 + cl2)) * 2 + d;
        gx4[idx] = f2bf(acc[fm][fn][q] + bias);
      }
    }
  }
}

// ---------------- k2: MFMA recurrence, raw barrier, running pointers --------
__global__ void __launch_bounds__(512, 1) gru_kernel(
    const unsigned short* __restrict__ Upk,
    const unsigned short* __restrict__ gx4,
    const int* __restrict__ x,
    const float* __restrict__ bfv, const float* __restrict__ bbv,
    float* __restrict__ out) {
  int wg = blockIdx.x;                 // 0..31
  int dir = wg >> 4, bg = wg & 15;
  int tid = threadIdx.x;
  int w = tid >> 6, l = tid & 63;
  int G = l >> 4, cl = l & 15;         // chain-in-group, unit-col
  int b = bg * 4 + G;

  // h[16 rows][256 units] bf16, byte ^= ((row&7)<<4) swizzle, double-buffered
  __shared__ __align__(16) unsigned short h_lds[2][4096];

  // resident U B-fragments: 6 slots x 8 K-frags = 192 regs
  short8 Ufr[6][8];
  {
    const unsigned short* ub = Upk + (size_t)(dir * 8 + w) * 24576 + (size_t)l * 8;
#pragma unroll
    for (int s = 0; s < 6; ++s)
#pragma unroll
      for (int kk = 0; kk < 8; ++kk)
        Ufr[s][kk] = __builtin_bit_cast(short8, *(const uint4*)(ub + (s * 8 + kk) * 512));
  }

  {
    uint4 z = {0u, 0u, 0u, 0u};
    ((uint4*)h_lds)[tid] = z;
    ((uint4*)h_lds)[512 + tid] = z;
  }

  const float* bv = dir ? bbv : bfv;
  float brh[2];
#pragma unroll
  for (int d = 0; d < 2; ++d) brh[d] = bv[1280 + w * 32 + d * 16 + cl];
  float* outb = out + ((size_t)b << 17);

  int amask = (cl & 7) << 4;
  float h_old[2] = {0.f, 0.f};

  // running pointers (byte-based), one step = 98304 B in gx4, 1 int in x
  int t0 = dir ? 511 : 0;
  long sdelta = dir ? -98304 : 98304;
  const char* gp = (const char*)gx4 + ((size_t)(dir * 512 + t0) * 98304)
                   + (size_t)((bg * 8 + w) * 64 + l) * 4;
  const int* xp = x + b * 512 + t0;
  int xdelta = dir ? -1 : 1;

  // prologue: load step 0's gx + mask
  unsigned int gq0 = *(const unsigned int*)(gp);
  unsigned int gq1 = *(const unsigned int*)(gp + 32768);
  unsigned int gq2 = *(const unsigned int*)(gp + 65536);
  int xv = *xp;
  __syncthreads();

  int cur = 0;
  int tcur = t0;
  for (int step = 0; step < 512; ++step) {
    // prefetch NEXT step (running pointers; redundant reload on last step)
    const char* gpn = (step < 511) ? gp + sdelta : gp;
    const int* xpn = (step < 511) ? xp + xdelta : xp;
    unsigned int gn0 = *(const unsigned int*)(gpn);
    unsigned int gn1 = *(const unsigned int*)(gpn + 32768);
    unsigned int gn2 = *(const unsigned int*)(gpn + 65536);
    int xn = *xpn;

    // --- MFMA phase: acc[s] = h @ U[slot s] ---
    f32x4 acc[6];
#pragma unroll
    for (int s = 0; s < 6; ++s) acc[s] = (f32x4){0.f, 0.f, 0.f, 0.f};
    const char* hb = (const char*)(&h_lds[cur][0]);
#pragma unroll
    for (int kk = 0; kk < 8; ++kk) {
      short8 a = __builtin_bit_cast(short8,
          *(const uint4*)(hb + cl * 512 + (((kk << 6) | (G << 4)) ^ amask)));
#pragma unroll
      for (int s = 0; s < 6; ++s)
        acc[s] = __builtin_amdgcn_mfma_f32_16x16x32_bf16(a, Ufr[s][kk], acc[s], 0, 0, 0);
    }

    // --- epilogue: chain G at C row 4G -> acc[s][0]; 2 units/lane ---
    char* hw = (char*)(&h_lds[cur ^ 1][0]);
#pragma unroll
    for (int d = 0; d < 2; ++d) {
      float gz = d ? bhi(gq0) : blo(gq0);
      float gr = d ? bhi(gq1) : blo(gq1);
      float gh = d ? bhi(gq2) : blo(gq2);
      float z = sigf(gz + acc[0 + d][0]);
      float r = sigf(gr + acc[2 + d][0]);
      float hh = tanhfast(gh + r * (acc[4 + d][0] + brh[d]));
      float hn = hh + z * (h_old[d] - hh);
      hn = (xv == 0) ? h_old[d] : hn;          // masked: carry state
      h_old[d] = hn;
      int u = w * 32 + d * 16 + cl;
      *(unsigned short*)(hw + G * 2048 + ((u * 2) ^ ((G & 1) << 6))) = f2bf(hn);
      atomicAdd(&outb[(size_t)tcur * 256 + u], hn);   // drains off-path now
    }
    lds_barrier();                              // LDS-only, no vmcnt drain
    gq0 = gn0; gq1 = gn1; gq2 = gn2; xv = xn;
    gp = gpn; xp = xpn;
    tcur += (step < 511) ? xdelta : 0;
    cur ^= 1;
  }
}

// ---------------------------------------------------------------------------
extern "C" void kernel_launch(void* const* d_in, const int* in_sizes, int n_in,
                              void* d_out, int out_size, void* d_ws, size_t ws_size,
                              hipStream_t stream) {
  const int*   x   = (const int*)d_in[0];
  const float* emb = (const float*)d_in[1];
  const float* Wf  = (const float*)d_in[2];
  const float* Uf  = (const float*)d_in[3];
  const float* bf_ = (const float*)d_in[4];
  const float* Wb  = (const float*)d_in[5];
  const float* Ub  = (const float*)d_in[6];
  const float* bb_ = (const float*)d_in[7];
  float* out = (float*)d_out;

  unsigned short* gx4 = (unsigned short*)d_ws;                        // 100663296 B
  unsigned short* Wtb = (unsigned short*)((char*)d_ws + 100663296);   // 786432 B
  unsigned short* Upk = (unsigned short*)((char*)d_ws + 100663296 + 786432);  // 786432 B

  hipMemsetAsync(d_out, 0, (size_t)out_size * sizeof(float), stream);

  wt_prep_kernel<<<1536, 256, 0, stream>>>(Wf, Wb, Wtb);
  u_prep_kernel<<<192, 256, 0, stream>>>(Uf, Ub, Upk);
  gx_mfma_kernel<<<dim3(256, 12), 256, 0, stream>>>(x, emb, Wtb, bf_, bb_, gx4);
  gru_kernel<<<32, 512, 0, stream>>>(Upk, gx4, x, bf_, bb_, out);
}